// Round 1
// baseline (712.918 us; speedup 1.0000x reference)
//
#include <hip/hip_runtime.h>

#define NNODES 100000
#define NEDGES 1600000
#define BN_EPS 1e-5f
#define L2_EPS 1e-12f

// ---------------------------------------------------------------------------
// cnt[dst] += 1 over all edges (layer-invariant)
__global__ void count_kernel(const int* __restrict__ dst, float* __restrict__ cnt) {
    int e = blockIdx.x * blockDim.x + threadIdx.x;
    if (e < NEDGES) atomicAdd(&cnt[dst[e]], 1.0f);
}

__global__ void invert_kernel(float* __restrict__ cnt) {
    int n = blockIdx.x * blockDim.x + threadIdx.x;
    if (n < NNODES) cnt[n] = 1.0f / fmaxf(cnt[n], 1.0f);
}

// ---------------------------------------------------------------------------
// s[dst[e]*C + c] += h[src[e]*C + c], one thread per (edge, channel)
template<int C>
__global__ void scatter_kernel(const int* __restrict__ src, const int* __restrict__ dst,
                               const float* __restrict__ h, float* __restrict__ s) {
    long t = (long)blockIdx.x * blockDim.x + threadIdx.x;
    if (t >= (long)NEDGES * C) return;
    int e = (int)(t / C);
    int c = (int)(t % C);
    atomicAdd(&s[dst[e] * C + c], h[src[e] * C + c]);
}

// ---------------------------------------------------------------------------
// Per-node: agg = s*inv_cnt; out = agg@WlT + bl + x@WrT; L2-normalize; ReLU.
// If DO_STATS: accumulate per-channel sum/sumsq for BatchNorm (block partials
// in LDS, one global atomicAdd per block per channel).
template<int CI, int CO, bool DO_STATS>
__global__ void node_kernel(const float* __restrict__ s, const float* __restrict__ inv_cnt,
                            const float* __restrict__ h_in,
                            const float* __restrict__ wl, const float* __restrict__ bl,
                            const float* __restrict__ wr,
                            float* __restrict__ y,
                            float* __restrict__ stat_sum, float* __restrict__ stat_sq) {
    __shared__ float sWl[CO * CI];
    __shared__ float sWr[CO * CI];
    __shared__ float sBl[CO];
    __shared__ float red_sum[CO];
    __shared__ float red_sq[CO];

    for (int i = threadIdx.x; i < CO * CI; i += blockDim.x) {
        sWl[i] = wl[i];
        sWr[i] = wr[i];
    }
    if (threadIdx.x < CO) {
        sBl[threadIdx.x] = bl[threadIdx.x];
        if (DO_STATS) { red_sum[threadIdx.x] = 0.0f; red_sq[threadIdx.x] = 0.0f; }
    }
    __syncthreads();

    int n = blockIdx.x * blockDim.x + threadIdx.x;
    bool valid = n < NNODES;

    float out[CO];
    if (valid) {
        float a[CI], xin[CI];
        float ic = inv_cnt[n];
#pragma unroll
        for (int c = 0; c < CI; c++) {
            a[c]   = s[n * CI + c] * ic;
            xin[c] = h_in[n * CI + c];
        }
        float nrm2 = 0.0f;
#pragma unroll
        for (int o = 0; o < CO; o++) {
            float acc = sBl[o];
#pragma unroll
            for (int c = 0; c < CI; c++)
                acc += sWl[o * CI + c] * a[c] + sWr[o * CI + c] * xin[c];
            out[o] = acc;
            nrm2 += acc * acc;
        }
        float inv_nrm = 1.0f / fmaxf(sqrtf(nrm2), L2_EPS);
#pragma unroll
        for (int o = 0; o < CO; o++) {
            float v = out[o] * inv_nrm;
            v = fmaxf(v, 0.0f);           // ReLU (applied in every layer)
            out[o] = v;
            y[n * CO + o] = v;
        }
    }

    if (DO_STATS) {
        if (valid) {
#pragma unroll
            for (int o = 0; o < CO; o++) {
                atomicAdd(&red_sum[o], out[o]);
                atomicAdd(&red_sq[o], out[o] * out[o]);
            }
        }
        __syncthreads();
        if (threadIdx.x < CO) {
            atomicAdd(&stat_sum[threadIdx.x], red_sum[threadIdx.x]);
            atomicAdd(&stat_sq[threadIdx.x], red_sq[threadIdx.x]);
        }
    }
}

// ---------------------------------------------------------------------------
// BatchNorm apply (training-mode batch stats, biased variance); in-place safe.
template<int C>
__global__ void bn_kernel(const float* __restrict__ y,
                          const float* __restrict__ ssum, const float* __restrict__ ssq,
                          const float* __restrict__ g, const float* __restrict__ b,
                          float* __restrict__ h_out) {
    __shared__ float scale[C];
    __shared__ float shift[C];
    if (threadIdx.x < C) {
        float m = ssum[threadIdx.x] * (1.0f / NNODES);
        float v = ssq[threadIdx.x] * (1.0f / NNODES) - m * m;
        float is = 1.0f / sqrtf(v + BN_EPS);
        float sc = g[threadIdx.x] * is;
        scale[threadIdx.x] = sc;
        shift[threadIdx.x] = b[threadIdx.x] - m * sc;
    }
    __syncthreads();
    long t = (long)blockIdx.x * blockDim.x + threadIdx.x;
    if (t < (long)NNODES * C) {
        int c = (int)(t % C);
        h_out[t] = y[t] * scale[c] + shift[c];
    }
}

// ---------------------------------------------------------------------------
extern "C" void kernel_launch(void* const* d_in, const int* in_sizes, int n_in,
                              void* d_out, int out_size, void* d_ws, size_t ws_size,
                              hipStream_t stream) {
    const float* x   = (const float*)d_in[0];
    const int*   ei  = (const int*)d_in[1];
    const int*   src = ei;
    const int*   dst = ei + NEDGES;

    const float* w1l = (const float*)d_in[2];
    const float* b1l = (const float*)d_in[3];
    const float* w1r = (const float*)d_in[4];
    const float* w2l = (const float*)d_in[5];
    const float* b2l = (const float*)d_in[6];
    const float* w2r = (const float*)d_in[7];
    const float* w3l = (const float*)d_in[8];
    const float* b3l = (const float*)d_in[9];
    const float* w3r = (const float*)d_in[10];
    const float* w4l = (const float*)d_in[11];
    const float* b4l = (const float*)d_in[12];
    const float* w4r = (const float*)d_in[13];
    const float* g1  = (const float*)d_in[14];
    const float* be1 = (const float*)d_in[15];
    const float* g2  = (const float*)d_in[16];
    const float* be2 = (const float*)d_in[17];
    const float* g3  = (const float*)d_in[18];
    const float* be3 = (const float*)d_in[19];

    float* ws      = (float*)d_ws;
    float* inv_cnt = ws;                          // N
    float* sbuf    = inv_cnt + NNODES;            // N*16 (max CI)
    float* hA      = sbuf + NNODES * 16;          // N*16
    float* hB      = hA + NNODES * 16;            // N*16
    float* stats   = hB + NNODES * 16;            // 64
    float* ssum    = stats;
    float* ssq     = stats + 32;

    const int BLK = 256;

    // degree count (once)
    hipMemsetAsync(inv_cnt, 0, NNODES * sizeof(float), stream);
    count_kernel<<<(NEDGES + BLK - 1) / BLK, BLK, 0, stream>>>(dst, inv_cnt);
    invert_kernel<<<(NNODES + BLK - 1) / BLK, BLK, 0, stream>>>(inv_cnt);

    // ---- layer 1: 4 -> 6, BN ----
    hipMemsetAsync(sbuf, 0, NNODES * 4 * sizeof(float), stream);
    hipMemsetAsync(stats, 0, 64 * sizeof(float), stream);
    scatter_kernel<4><<<(NEDGES * 4 + BLK - 1) / BLK, BLK, 0, stream>>>(src, dst, x, sbuf);
    node_kernel<4, 6, true><<<(NNODES + BLK - 1) / BLK, BLK, 0, stream>>>(
        sbuf, inv_cnt, x, w1l, b1l, w1r, hA, ssum, ssq);
    bn_kernel<6><<<((long)NNODES * 6 + BLK - 1) / BLK, BLK, 0, stream>>>(
        hA, ssum, ssq, g1, be1, hA);

    // ---- layer 2: 6 -> 8, BN ----
    hipMemsetAsync(sbuf, 0, NNODES * 6 * sizeof(float), stream);
    hipMemsetAsync(stats, 0, 64 * sizeof(float), stream);
    scatter_kernel<6><<<(NEDGES * 6 + BLK - 1) / BLK, BLK, 0, stream>>>(src, dst, hA, sbuf);
    node_kernel<6, 8, true><<<(NNODES + BLK - 1) / BLK, BLK, 0, stream>>>(
        sbuf, inv_cnt, hA, w2l, b2l, w2r, hB, ssum, ssq);
    bn_kernel<8><<<((long)NNODES * 8 + BLK - 1) / BLK, BLK, 0, stream>>>(
        hB, ssum, ssq, g2, be2, hB);

    // ---- layer 3: 8 -> 16, BN ----
    hipMemsetAsync(sbuf, 0, NNODES * 8 * sizeof(float), stream);
    hipMemsetAsync(stats, 0, 64 * sizeof(float), stream);
    scatter_kernel<8><<<(NEDGES * 8 + BLK - 1) / BLK, BLK, 0, stream>>>(src, dst, hB, sbuf);
    node_kernel<8, 16, true><<<(NNODES + BLK - 1) / BLK, BLK, 0, stream>>>(
        sbuf, inv_cnt, hB, w3l, b3l, w3r, hA, ssum, ssq);
    bn_kernel<16><<<((long)NNODES * 16 + BLK - 1) / BLK, BLK, 0, stream>>>(
        hA, ssum, ssq, g3, be3, hA);

    // ---- layer 4: 16 -> 32, no BN, ReLU -> d_out ----
    hipMemsetAsync(sbuf, 0, NNODES * 16 * sizeof(float), stream);
    scatter_kernel<16><<<((long)NEDGES * 16 + BLK - 1) / BLK, BLK, 0, stream>>>(src, dst, hA, sbuf);
    node_kernel<16, 32, false><<<(NNODES + BLK - 1) / BLK, BLK, 0, stream>>>(
        sbuf, inv_cnt, hA, w4l, b4l, w4r, (float*)d_out, nullptr, nullptr);
}

// Round 2
// 512.276 us; speedup vs baseline: 1.3917x; 1.3917x over previous
//
#include <hip/hip_runtime.h>

#define NNODES 100000
#define NEDGES 1600000
#define BN_EPS 1e-5f
#define L2_EPS 1e-12f
#define NB_SCAN 391   // ceil(NNODES/256)

// ---------------------------------------------------------------------------
// CSR build: degree -> prefix scan -> fill (dst-sorted src list)
__global__ void degree_kernel(const int* __restrict__ dst, int* __restrict__ deg) {
    int e = blockIdx.x * blockDim.x + threadIdx.x;
    if (e < NEDGES) atomicAdd(&deg[dst[e]], 1);
}

__global__ void scan_local(const int* __restrict__ deg, int* __restrict__ row_tmp,
                           int* __restrict__ bsum) {
    __shared__ int tmp[256];
    int i = blockIdx.x * 256 + threadIdx.x;
    int v = (i < NNODES) ? deg[i] : 0;
    tmp[threadIdx.x] = v;
    __syncthreads();
    for (int off = 1; off < 256; off <<= 1) {
        int t = (threadIdx.x >= off) ? tmp[threadIdx.x - off] : 0;
        __syncthreads();
        tmp[threadIdx.x] += t;
        __syncthreads();
    }
    if (i < NNODES) row_tmp[i] = tmp[threadIdx.x] - v;   // exclusive
    if (threadIdx.x == 255) bsum[blockIdx.x] = tmp[255];
}

__global__ void scan_bsums(int* __restrict__ bsum) {
    __shared__ int tmp[512];
    int v = (threadIdx.x < NB_SCAN) ? bsum[threadIdx.x] : 0;
    tmp[threadIdx.x] = v;
    __syncthreads();
    for (int off = 1; off < 512; off <<= 1) {
        int t = (threadIdx.x >= off) ? tmp[threadIdx.x - off] : 0;
        __syncthreads();
        tmp[threadIdx.x] += t;
        __syncthreads();
    }
    if (threadIdx.x < NB_SCAN) bsum[threadIdx.x] = tmp[threadIdx.x] - v;  // exclusive
}

__global__ void scan_add(const int* __restrict__ row_tmp, const int* __restrict__ bsum,
                         int* __restrict__ row_ptr, int* __restrict__ cursor) {
    int i = blockIdx.x * 256 + threadIdx.x;
    if (i < NNODES) {
        int v = row_tmp[i] + bsum[blockIdx.x];
        row_ptr[i] = v;
        cursor[i]  = v;
    }
    if (i == 0) row_ptr[NNODES] = NEDGES;
}

__global__ void fill_kernel(const int* __restrict__ src, const int* __restrict__ dst,
                            int* __restrict__ cursor, int* __restrict__ col) {
    int e = blockIdx.x * blockDim.x + threadIdx.x;
    if (e < NEDGES) {
        int p = atomicAdd(&cursor[dst[e]], 1);
        col[p] = src[e];
    }
}

// ---------------------------------------------------------------------------
// Fused layer: gather-mean neighbors (applying previous layer's BN affine on
// the fly), dense out = agg@WlT + bl + x@WrT, row L2-norm, ReLU; optionally
// accumulate BN batch stats (LDS partials -> 1 global atomic/block/channel).
template<int CI, int CO, bool IN_AFFINE, bool DO_STATS>
__global__ void layer_kernel(const int* __restrict__ row_ptr, const int* __restrict__ col,
                             const float* __restrict__ h,
                             const float* __restrict__ sc_in, const float* __restrict__ sh_in,
                             const float* __restrict__ wl, const float* __restrict__ bl,
                             const float* __restrict__ wr,
                             float* __restrict__ y,
                             float* __restrict__ stat_sum, float* __restrict__ stat_sq) {
    __shared__ float sWl[CO * CI];
    __shared__ float sWr[CO * CI];
    __shared__ float sBl[CO];
    __shared__ float sSc[CI];
    __shared__ float sSh[CI];
    __shared__ float red_sum[CO];
    __shared__ float red_sq[CO];

    for (int i = threadIdx.x; i < CO * CI; i += blockDim.x) {
        sWl[i] = wl[i];
        sWr[i] = wr[i];
    }
    if (threadIdx.x < CO) {
        sBl[threadIdx.x] = bl[threadIdx.x];
        if (DO_STATS) { red_sum[threadIdx.x] = 0.0f; red_sq[threadIdx.x] = 0.0f; }
    }
    if (IN_AFFINE && threadIdx.x < CI) {
        sSc[threadIdx.x] = sc_in[threadIdx.x];
        sSh[threadIdx.x] = sh_in[threadIdx.x];
    }
    __syncthreads();

    int n = blockIdx.x * blockDim.x + threadIdx.x;
    bool valid = n < NNODES;

    float out[CO];
    if (valid) {
        int beg = row_ptr[n], end = row_ptr[n + 1];

        constexpr int U = (CI <= 8) ? 4 : 2;
        float acc[U][CI];
#pragma unroll
        for (int u = 0; u < U; u++)
#pragma unroll
            for (int c = 0; c < CI; c++) acc[u][c] = 0.0f;

        int j = beg;
        for (; j + U <= end; j += U) {
            int idx[U];
#pragma unroll
            for (int u = 0; u < U; u++) idx[u] = col[j + u];
#pragma unroll
            for (int u = 0; u < U; u++) {
                const float* p = h + idx[u] * CI;
#pragma unroll
                for (int c = 0; c < CI; c++) acc[u][c] += p[c];
            }
        }
        for (; j < end; j++) {
            const float* p = h + col[j] * CI;
#pragma unroll
            for (int c = 0; c < CI; c++) acc[0][c] += p[c];
        }
#pragma unroll
        for (int u = 1; u < U; u++)
#pragma unroll
            for (int c = 0; c < CI; c++) acc[0][c] += acc[u][c];

        float ic = 1.0f / fmaxf((float)(end - beg), 1.0f);
        float agg[CI], xin[CI];
#pragma unroll
        for (int c = 0; c < CI; c++) {
            float a = acc[0][c] * ic;
            float xv = h[n * CI + c];
            if (IN_AFFINE) {
                a  = a  * sSc[c] + sSh[c];
                xv = xv * sSc[c] + sSh[c];
            }
            agg[c] = a;
            xin[c] = xv;
        }

        float nrm2 = 0.0f;
#pragma unroll
        for (int o = 0; o < CO; o++) {
            float v = sBl[o];
#pragma unroll
            for (int c = 0; c < CI; c++)
                v += sWl[o * CI + c] * agg[c] + sWr[o * CI + c] * xin[c];
            out[o] = v;
            nrm2 += v * v;
        }
        float inv_nrm = 1.0f / fmaxf(sqrtf(nrm2), L2_EPS);
#pragma unroll
        for (int o = 0; o < CO; o++) {
            float v = fmaxf(out[o] * inv_nrm, 0.0f);   // L2 norm + ReLU
            out[o] = v;
            y[n * CO + o] = v;
        }
    }

    if (DO_STATS) {
        if (valid) {
#pragma unroll
            for (int o = 0; o < CO; o++) {
                atomicAdd(&red_sum[o], out[o]);
                atomicAdd(&red_sq[o], out[o] * out[o]);
            }
        }
        __syncthreads();
        if (threadIdx.x < CO) {
            atomicAdd(&stat_sum[threadIdx.x], red_sum[threadIdx.x]);
            atomicAdd(&stat_sq[threadIdx.x], red_sq[threadIdx.x]);
        }
    }
}

// ---------------------------------------------------------------------------
// BN stats -> per-channel affine (sc, sh):  y_bn = y*sc + sh
__global__ void finalize_bn(const float* __restrict__ ssum, const float* __restrict__ ssq,
                            const float* __restrict__ g, const float* __restrict__ b,
                            float* __restrict__ sc, float* __restrict__ sh, int C) {
    int c = threadIdx.x;
    if (c < C) {
        float m = ssum[c] * (1.0f / NNODES);
        float v = ssq[c] * (1.0f / NNODES) - m * m;
        float is = 1.0f / sqrtf(v + BN_EPS);
        float s = g[c] * is;
        sc[c] = s;
        sh[c] = b[c] - m * s;
    }
}

// ---------------------------------------------------------------------------
extern "C" void kernel_launch(void* const* d_in, const int* in_sizes, int n_in,
                              void* d_out, int out_size, void* d_ws, size_t ws_size,
                              hipStream_t stream) {
    const float* x   = (const float*)d_in[0];
    const int*   ei  = (const int*)d_in[1];
    const int*   src = ei;
    const int*   dst = ei + NEDGES;

    const float* w1l = (const float*)d_in[2];
    const float* b1l = (const float*)d_in[3];
    const float* w1r = (const float*)d_in[4];
    const float* w2l = (const float*)d_in[5];
    const float* b2l = (const float*)d_in[6];
    const float* w2r = (const float*)d_in[7];
    const float* w3l = (const float*)d_in[8];
    const float* b3l = (const float*)d_in[9];
    const float* w3r = (const float*)d_in[10];
    const float* w4l = (const float*)d_in[11];
    const float* b4l = (const float*)d_in[12];
    const float* w4r = (const float*)d_in[13];
    const float* g1  = (const float*)d_in[14];
    const float* be1 = (const float*)d_in[15];
    const float* g2  = (const float*)d_in[16];
    const float* be2 = (const float*)d_in[17];
    const float* g3  = (const float*)d_in[18];
    const float* be3 = (const float*)d_in[19];

    char* w = (char*)d_ws;
    int*   deg     = (int*)w;              w += NNODES * 4;
    int*   row_tmp = (int*)w;              w += NNODES * 4;
    int*   bsum    = (int*)w;              w += 512 * 4;
    int*   row_ptr = (int*)w;              w += (NNODES + 8) * 4;
    int*   cursor  = (int*)w;              w += NNODES * 4;
    int*   col     = (int*)w;              w += NEDGES * 4;
    float* hA      = (float*)w;            w += NNODES * 16 * 4;
    float* hB      = (float*)w;            w += NNODES * 16 * 4;
    float* stats   = (float*)w;            w += 3 * 128 * 4;
    // per layer k (0..2): ssum[32] ssq[32] sc[32] sh[32]
    float* ssum1 = stats + 0 * 128, *ssq1 = ssum1 + 32, *sc1 = ssq1 + 32, *sh1 = sc1 + 32;
    float* ssum2 = stats + 1 * 128, *ssq2 = ssum2 + 32, *sc2 = ssq2 + 32, *sh2 = sc2 + 32;
    float* ssum3 = stats + 2 * 128, *ssq3 = ssum3 + 32, *sc3 = ssq3 + 32, *sh3 = sc3 + 32;

    const int BLK = 256;
    const int EB  = (NEDGES + BLK - 1) / BLK;

    hipMemsetAsync(deg, 0, NNODES * 4, stream);
    hipMemsetAsync(stats, 0, 3 * 128 * 4, stream);

    // CSR build
    degree_kernel<<<EB, BLK, 0, stream>>>(dst, deg);
    scan_local<<<NB_SCAN, 256, 0, stream>>>(deg, row_tmp, bsum);
    scan_bsums<<<1, 512, 0, stream>>>(bsum);
    scan_add<<<NB_SCAN, 256, 0, stream>>>(row_tmp, bsum, row_ptr, cursor);
    fill_kernel<<<EB, BLK, 0, stream>>>(src, dst, cursor, col);

    // layer 1: 4 -> 6 (+stats)
    layer_kernel<4, 6, false, true><<<NB_SCAN, BLK, 0, stream>>>(
        row_ptr, col, x, nullptr, nullptr, w1l, b1l, w1r, hA, ssum1, ssq1);
    finalize_bn<<<1, 64, 0, stream>>>(ssum1, ssq1, g1, be1, sc1, sh1, 6);

    // layer 2: 6 -> 8 (+stats), BN1 folded into gather
    layer_kernel<6, 8, true, true><<<NB_SCAN, BLK, 0, stream>>>(
        row_ptr, col, hA, sc1, sh1, w2l, b2l, w2r, hB, ssum2, ssq2);
    finalize_bn<<<1, 64, 0, stream>>>(ssum2, ssq2, g2, be2, sc2, sh2, 8);

    // layer 3: 8 -> 16 (+stats), BN2 folded
    layer_kernel<8, 16, true, true><<<NB_SCAN, BLK, 0, stream>>>(
        row_ptr, col, hB, sc2, sh2, w3l, b3l, w3r, hA, ssum3, ssq3);
    finalize_bn<<<1, 64, 0, stream>>>(ssum3, ssq3, g3, be3, sc3, sh3, 16);

    // layer 4: 16 -> 32, BN3 folded, ReLU -> d_out
    layer_kernel<16, 32, true, false><<<NB_SCAN, BLK, 0, stream>>>(
        row_ptr, col, hA, sc3, sh3, w4l, b4l, w4r, (float*)d_out, nullptr, nullptr);
}

// Round 3
// 366.651 us; speedup vs baseline: 1.9444x; 1.3972x over previous
//
#include <hip/hip_runtime.h>

#define NNODES 100000
#define NEDGES 1600000
#define BN_EPS 1e-5f
#define L2_EPS 1e-12f

#define BKT_SHIFT 9
#define BKT_SIZE  512
#define NBKT      196            // ceil(100000/512)
#define CHUNK     4096
#define NBLK_E    391            // ceil(1600000/4096)
#define NB_NODE   391            // ceil(100000/256)

// ---------------------------------------------------------------------------
// Pass 1: per-block bucket histogram (LDS), dense output + bucket totals
__global__ void hist_kernel(const int* __restrict__ dst,
                            int* __restrict__ blk_hist, int* __restrict__ bucket_total) {
    __shared__ int h[NBKT];
    for (int i = threadIdx.x; i < NBKT; i += blockDim.x) h[i] = 0;
    __syncthreads();
    int base = blockIdx.x * CHUNK;
    int end  = min(base + CHUNK, NEDGES);
    for (int e = base + threadIdx.x; e < end; e += blockDim.x)
        atomicAdd(&h[dst[e] >> BKT_SHIFT], 1);
    __syncthreads();
    for (int i = threadIdx.x; i < NBKT; i += blockDim.x) {
        int v = h[i];
        blk_hist[blockIdx.x * NBKT + i] = v;
        if (v) atomicAdd(&bucket_total[i], v);
    }
}

// exclusive scan of bucket totals -> bucket_base[NBKT+1]
__global__ void scan_buckets(const int* __restrict__ bucket_total, int* __restrict__ bucket_base) {
    __shared__ int tmp[256];
    int v = (threadIdx.x < NBKT) ? bucket_total[threadIdx.x] : 0;
    tmp[threadIdx.x] = v;
    __syncthreads();
    for (int off = 1; off < 256; off <<= 1) {
        int t = (threadIdx.x >= off) ? tmp[threadIdx.x - off] : 0;
        __syncthreads();
        tmp[threadIdx.x] += t;
        __syncthreads();
    }
    if (threadIdx.x < NBKT) bucket_base[threadIdx.x] = tmp[threadIdx.x] - v;
    if (threadIdx.x == 0) bucket_base[NBKT] = NEDGES;
}

// per-bucket exclusive scan across blocks: exact (block,bucket) write offsets
__global__ void scan_blocks(const int* __restrict__ blk_hist, const int* __restrict__ bucket_base,
                            int* __restrict__ blk_off) {
    __shared__ int tmp[512];
    int b = blockIdx.x;
    int i = threadIdx.x;
    int v = (i < NBLK_E) ? blk_hist[i * NBKT + b] : 0;
    tmp[i] = v;
    __syncthreads();
    for (int off = 1; off < 512; off <<= 1) {
        int t = (i >= off) ? tmp[i - off] : 0;
        __syncthreads();
        tmp[i] += t;
        __syncthreads();
    }
    if (i < NBLK_E) blk_off[i * NBKT + b] = bucket_base[b] + tmp[i] - v;
}

// Pass 2: scatter edges into bucket segments (packed: dst_local<<23 | src). No global atomics.
__global__ void bucket_scatter(const int* __restrict__ src, const int* __restrict__ dst,
                               const int* __restrict__ blk_off, unsigned int* __restrict__ staged) {
    __shared__ int cur[NBKT];
    for (int i = threadIdx.x; i < NBKT; i += blockDim.x)
        cur[i] = blk_off[blockIdx.x * NBKT + i];
    __syncthreads();
    int base = blockIdx.x * CHUNK;
    int end  = min(base + CHUNK, NEDGES);
    for (int e = base + threadIdx.x; e < end; e += blockDim.x) {
        int d = dst[e];
        int b = d >> BKT_SHIFT;
        int p = atomicAdd(&cur[b], 1);          // LDS atomic only
        staged[p] = ((unsigned)(d & (BKT_SIZE - 1)) << 23) | (unsigned)src[e];
    }
}

// Pass 3: one block per bucket -> exact CSR (row_ptr + node-sorted col).
// All col writes land in this bucket's <=64KB region (single CU/XCD).
__global__ void csr_finalize(const unsigned int* __restrict__ staged,
                             const int* __restrict__ bucket_base,
                             int* __restrict__ row_ptr, int* __restrict__ col) {
    __shared__ int nh[BKT_SIZE];
    __shared__ int cur[BKT_SIZE];
    int b = blockIdx.x;
    int beg = bucket_base[b], end = bucket_base[b + 1];

    nh[threadIdx.x] = 0;
    __syncthreads();
    for (int e = beg + threadIdx.x; e < end; e += blockDim.x)
        atomicAdd(&nh[staged[e] >> 23], 1);
    __syncthreads();

    int v = nh[threadIdx.x];
    cur[threadIdx.x] = v;
    __syncthreads();
    for (int off = 1; off < 512; off <<= 1) {
        int t = (threadIdx.x >= off) ? cur[threadIdx.x - off] : 0;
        __syncthreads();
        cur[threadIdx.x] += t;
        __syncthreads();
    }
    int excl = cur[threadIdx.x] - v;

    int node = b * BKT_SIZE + threadIdx.x;
    if (node < NNODES) row_ptr[node] = beg + excl;
    if (b == 0 && threadIdx.x == 0) row_ptr[NNODES] = NEDGES;
    __syncthreads();
    cur[threadIdx.x] = excl;
    __syncthreads();

    for (int e = beg + threadIdx.x; e < end; e += blockDim.x) {
        unsigned pk = staged[e];
        int l = (int)(pk >> 23);
        int p = atomicAdd(&cur[l], 1);          // LDS atomic only
        col[beg + p] = (int)(pk & 0x7FFFFF);
    }
}

// ---------------------------------------------------------------------------
// Fused layer: gather-mean (prev BN affine folded), dense matmul, L2 norm,
// ReLU, optional BN stats (LDS partials -> 1 global atomic/block/channel).
template<int CI, int CO, bool IN_AFFINE, bool DO_STATS>
__global__ void layer_kernel(const int* __restrict__ row_ptr, const int* __restrict__ col,
                             const float* __restrict__ h,
                             const float* __restrict__ sc_in, const float* __restrict__ sh_in,
                             const float* __restrict__ wl, const float* __restrict__ bl,
                             const float* __restrict__ wr,
                             float* __restrict__ y,
                             float* __restrict__ stat_sum, float* __restrict__ stat_sq) {
    __shared__ float sWl[CO * CI];
    __shared__ float sWr[CO * CI];
    __shared__ float sBl[CO];
    __shared__ float sSc[CI];
    __shared__ float sSh[CI];
    __shared__ float red_sum[CO];
    __shared__ float red_sq[CO];

    for (int i = threadIdx.x; i < CO * CI; i += blockDim.x) {
        sWl[i] = wl[i];
        sWr[i] = wr[i];
    }
    if (threadIdx.x < CO) {
        sBl[threadIdx.x] = bl[threadIdx.x];
        if (DO_STATS) { red_sum[threadIdx.x] = 0.0f; red_sq[threadIdx.x] = 0.0f; }
    }
    if (IN_AFFINE && threadIdx.x < CI) {
        sSc[threadIdx.x] = sc_in[threadIdx.x];
        sSh[threadIdx.x] = sh_in[threadIdx.x];
    }
    __syncthreads();

    int n = blockIdx.x * blockDim.x + threadIdx.x;
    bool valid = n < NNODES;

    float out[CO];
    if (valid) {
        int beg = row_ptr[n], end = row_ptr[n + 1];

        constexpr int U = (CI <= 8) ? 4 : 2;
        float acc[U][CI];
#pragma unroll
        for (int u = 0; u < U; u++)
#pragma unroll
            for (int c = 0; c < CI; c++) acc[u][c] = 0.0f;

        int j = beg;
        for (; j + U <= end; j += U) {
            int idx[U];
#pragma unroll
            for (int u = 0; u < U; u++) idx[u] = col[j + u];
#pragma unroll
            for (int u = 0; u < U; u++) {
                const float* p = h + idx[u] * CI;
#pragma unroll
                for (int c = 0; c < CI; c++) acc[u][c] += p[c];
            }
        }
        for (; j < end; j++) {
            const float* p = h + col[j] * CI;
#pragma unroll
            for (int c = 0; c < CI; c++) acc[0][c] += p[c];
        }
#pragma unroll
        for (int u = 1; u < U; u++)
#pragma unroll
            for (int c = 0; c < CI; c++) acc[0][c] += acc[u][c];

        float ic = 1.0f / fmaxf((float)(end - beg), 1.0f);
        float agg[CI], xin[CI];
#pragma unroll
        for (int c = 0; c < CI; c++) {
            float a  = acc[0][c] * ic;
            float xv = h[n * CI + c];
            if (IN_AFFINE) {
                a  = a  * sSc[c] + sSh[c];
                xv = xv * sSc[c] + sSh[c];
            }
            agg[c] = a;
            xin[c] = xv;
        }

        float nrm2 = 0.0f;
#pragma unroll
        for (int o = 0; o < CO; o++) {
            float v = sBl[o];
#pragma unroll
            for (int c = 0; c < CI; c++)
                v += sWl[o * CI + c] * agg[c] + sWr[o * CI + c] * xin[c];
            out[o] = v;
            nrm2 += v * v;
        }
        float inv_nrm = 1.0f / fmaxf(sqrtf(nrm2), L2_EPS);
#pragma unroll
        for (int o = 0; o < CO; o++) {
            float v = fmaxf(out[o] * inv_nrm, 0.0f);   // L2 norm + ReLU
            out[o] = v;
            y[n * CO + o] = v;
        }
    }

    if (DO_STATS) {
        if (valid) {
#pragma unroll
            for (int o = 0; o < CO; o++) {
                atomicAdd(&red_sum[o], out[o]);
                atomicAdd(&red_sq[o], out[o] * out[o]);
            }
        }
        __syncthreads();
        if (threadIdx.x < CO) {
            atomicAdd(&stat_sum[threadIdx.x], red_sum[threadIdx.x]);
            atomicAdd(&stat_sq[threadIdx.x], red_sq[threadIdx.x]);
        }
    }
}

// BN stats -> per-channel affine (sc, sh):  y_bn = y*sc + sh
__global__ void finalize_bn(const float* __restrict__ ssum, const float* __restrict__ ssq,
                            const float* __restrict__ g, const float* __restrict__ b,
                            float* __restrict__ sc, float* __restrict__ sh, int C) {
    int c = threadIdx.x;
    if (c < C) {
        float m = ssum[c] * (1.0f / NNODES);
        float v = ssq[c] * (1.0f / NNODES) - m * m;
        float is = 1.0f / sqrtf(v + BN_EPS);
        float s = g[c] * is;
        sc[c] = s;
        sh[c] = b[c] - m * s;
    }
}

// ---------------------------------------------------------------------------
extern "C" void kernel_launch(void* const* d_in, const int* in_sizes, int n_in,
                              void* d_out, int out_size, void* d_ws, size_t ws_size,
                              hipStream_t stream) {
    const float* x   = (const float*)d_in[0];
    const int*   ei  = (const int*)d_in[1];
    const int*   src = ei;
    const int*   dst = ei + NEDGES;

    const float* w1l = (const float*)d_in[2];
    const float* b1l = (const float*)d_in[3];
    const float* w1r = (const float*)d_in[4];
    const float* w2l = (const float*)d_in[5];
    const float* b2l = (const float*)d_in[6];
    const float* w2r = (const float*)d_in[7];
    const float* w3l = (const float*)d_in[8];
    const float* b3l = (const float*)d_in[9];
    const float* w3r = (const float*)d_in[10];
    const float* w4l = (const float*)d_in[11];
    const float* b4l = (const float*)d_in[12];
    const float* w4r = (const float*)d_in[13];
    const float* g1  = (const float*)d_in[14];
    const float* be1 = (const float*)d_in[15];
    const float* g2  = (const float*)d_in[16];
    const float* be2 = (const float*)d_in[17];
    const float* g3  = (const float*)d_in[18];
    const float* be3 = (const float*)d_in[19];

    char* w = (char*)d_ws;
    int* blk_hist     = (int*)w;  w += NBLK_E * NBKT * 4;      // 306 KB
    int* blk_off      = (int*)w;  w += NBLK_E * NBKT * 4;      // 306 KB
    int* bucket_total = (int*)w;  w += 256 * 4;
    int* bucket_base  = (int*)w;  w += 256 * 4;
    int* row_ptr      = (int*)w;  w += (NNODES + 8) * 4;       // 400 KB
    int* col          = (int*)w;  w += NEDGES * 4;             // 6.4 MB
    float* hA         = (float*)w; w += NNODES * 16 * 4;       // 6.4 MB
    float* hB         = (float*)w; w += NNODES * 16 * 4;       // 6.4 MB
    float* stats      = (float*)w; w += 3 * 128 * 4;
    unsigned int* staged = (unsigned int*)hB;  // staged edges die before hB is written

    float* ssum1 = stats + 0 * 128, *ssq1 = ssum1 + 32, *sc1 = ssq1 + 32, *sh1 = sc1 + 32;
    float* ssum2 = stats + 1 * 128, *ssq2 = ssum2 + 32, *sc2 = ssq2 + 32, *sh2 = sc2 + 32;
    float* ssum3 = stats + 2 * 128, *ssq3 = ssum3 + 32, *sc3 = ssq3 + 32, *sh3 = sc3 + 32;

    hipMemsetAsync(bucket_total, 0, 256 * 4, stream);
    hipMemsetAsync(stats, 0, 3 * 128 * 4, stream);

    // atomic-free CSR build (counting sort by dst bucket)
    hist_kernel   <<<NBLK_E, 256, 0, stream>>>(dst, blk_hist, bucket_total);
    scan_buckets  <<<1, 256, 0, stream>>>(bucket_total, bucket_base);
    scan_blocks   <<<NBKT, 512, 0, stream>>>(blk_hist, bucket_base, blk_off);
    bucket_scatter<<<NBLK_E, 256, 0, stream>>>(src, dst, blk_off, staged);
    csr_finalize  <<<NBKT, 512, 0, stream>>>(staged, bucket_base, row_ptr, col);

    // layer 1: 4 -> 6 (+stats)
    layer_kernel<4, 6, false, true><<<NB_NODE, 256, 0, stream>>>(
        row_ptr, col, x, nullptr, nullptr, w1l, b1l, w1r, hA, ssum1, ssq1);
    finalize_bn<<<1, 64, 0, stream>>>(ssum1, ssq1, g1, be1, sc1, sh1, 6);

    // layer 2: 6 -> 8 (+stats), BN1 folded (hB clobbers staged: OK, dead)
    layer_kernel<6, 8, true, true><<<NB_NODE, 256, 0, stream>>>(
        row_ptr, col, hA, sc1, sh1, w2l, b2l, w2r, hB, ssum2, ssq2);
    finalize_bn<<<1, 64, 0, stream>>>(ssum2, ssq2, g2, be2, sc2, sh2, 8);

    // layer 3: 8 -> 16 (+stats), BN2 folded
    layer_kernel<8, 16, true, true><<<NB_NODE, 256, 0, stream>>>(
        row_ptr, col, hB, sc2, sh2, w3l, b3l, w3r, hA, ssum3, ssq3);
    finalize_bn<<<1, 64, 0, stream>>>(ssum3, ssq3, g3, be3, sc3, sh3, 16);

    // layer 4: 16 -> 32, BN3 folded, ReLU -> d_out
    layer_kernel<16, 32, true, false><<<NB_NODE, 256, 0, stream>>>(
        row_ptr, col, hA, sc3, sh3, w4l, b4l, w4r, (float*)d_out, nullptr, nullptr);
}

// Round 4
// 302.765 us; speedup vs baseline: 2.3547x; 1.2110x over previous
//
#include <hip/hip_runtime.h>

#define NNODES 100000
#define NEDGES 1600000
#define BN_EPS 1e-5f
#define L2_EPS 1e-12f

#define BKT_SHIFT 9
#define BKT_SIZE  512
#define NBKT      196            // ceil(100000/512)
#define CHUNK     4096
#define NBLK_E    391            // ceil(1600000/4096)

// ---------------------------------------------------------------------------
// CSR build (atomic-free counting sort by dst bucket) — unchanged from R3
__global__ void hist_kernel(const int* __restrict__ dst,
                            int* __restrict__ blk_hist, int* __restrict__ bucket_total) {
    __shared__ int h[NBKT];
    for (int i = threadIdx.x; i < NBKT; i += blockDim.x) h[i] = 0;
    __syncthreads();
    int base = blockIdx.x * CHUNK;
    int end  = min(base + CHUNK, NEDGES);
    for (int e = base + threadIdx.x; e < end; e += blockDim.x)
        atomicAdd(&h[dst[e] >> BKT_SHIFT], 1);
    __syncthreads();
    for (int i = threadIdx.x; i < NBKT; i += blockDim.x) {
        int v = h[i];
        blk_hist[blockIdx.x * NBKT + i] = v;
        if (v) atomicAdd(&bucket_total[i], v);
    }
}

__global__ void scan_buckets(const int* __restrict__ bucket_total, int* __restrict__ bucket_base) {
    __shared__ int tmp[256];
    int v = (threadIdx.x < NBKT) ? bucket_total[threadIdx.x] : 0;
    tmp[threadIdx.x] = v;
    __syncthreads();
    for (int off = 1; off < 256; off <<= 1) {
        int t = (threadIdx.x >= off) ? tmp[threadIdx.x - off] : 0;
        __syncthreads();
        tmp[threadIdx.x] += t;
        __syncthreads();
    }
    if (threadIdx.x < NBKT) bucket_base[threadIdx.x] = tmp[threadIdx.x] - v;
    if (threadIdx.x == 0) bucket_base[NBKT] = NEDGES;
}

__global__ void scan_blocks(const int* __restrict__ blk_hist, const int* __restrict__ bucket_base,
                            int* __restrict__ blk_off) {
    __shared__ int tmp[512];
    int b = blockIdx.x;
    int i = threadIdx.x;
    int v = (i < NBLK_E) ? blk_hist[i * NBKT + b] : 0;
    tmp[i] = v;
    __syncthreads();
    for (int off = 1; off < 512; off <<= 1) {
        int t = (i >= off) ? tmp[i - off] : 0;
        __syncthreads();
        tmp[i] += t;
        __syncthreads();
    }
    if (i < NBLK_E) blk_off[i * NBKT + b] = bucket_base[b] + tmp[i] - v;
}

__global__ void bucket_scatter(const int* __restrict__ src, const int* __restrict__ dst,
                               const int* __restrict__ blk_off, unsigned int* __restrict__ staged) {
    __shared__ int cur[NBKT];
    for (int i = threadIdx.x; i < NBKT; i += blockDim.x)
        cur[i] = blk_off[blockIdx.x * NBKT + i];
    __syncthreads();
    int base = blockIdx.x * CHUNK;
    int end  = min(base + CHUNK, NEDGES);
    for (int e = base + threadIdx.x; e < end; e += blockDim.x) {
        int d = dst[e];
        int b = d >> BKT_SHIFT;
        int p = atomicAdd(&cur[b], 1);          // LDS atomic only
        staged[p] = ((unsigned)(d & (BKT_SIZE - 1)) << 23) | (unsigned)src[e];
    }
}

__global__ void csr_finalize(const unsigned int* __restrict__ staged,
                             const int* __restrict__ bucket_base,
                             int* __restrict__ row_ptr, int* __restrict__ col) {
    __shared__ int nh[BKT_SIZE];
    __shared__ int cur[BKT_SIZE];
    int b = blockIdx.x;
    int beg = bucket_base[b], end = bucket_base[b + 1];

    nh[threadIdx.x] = 0;
    __syncthreads();
    for (int e = beg + threadIdx.x; e < end; e += blockDim.x)
        atomicAdd(&nh[staged[e] >> 23], 1);
    __syncthreads();

    int v = nh[threadIdx.x];
    cur[threadIdx.x] = v;
    __syncthreads();
    for (int off = 1; off < 512; off <<= 1) {
        int t = (threadIdx.x >= off) ? cur[threadIdx.x - off] : 0;
        __syncthreads();
        cur[threadIdx.x] += t;
        __syncthreads();
    }
    int excl = cur[threadIdx.x] - v;

    int node = b * BKT_SIZE + threadIdx.x;
    if (node < NNODES) row_ptr[node] = beg + excl;
    if (b == 0 && threadIdx.x == 0) row_ptr[NNODES] = NEDGES;
    __syncthreads();
    cur[threadIdx.x] = excl;
    __syncthreads();

    for (int e = beg + threadIdx.x; e < end; e += blockDim.x) {
        unsigned pk = staged[e];
        int l = (int)(pk >> 23);
        int p = atomicAdd(&cur[l], 1);          // LDS atomic only
        col[beg + p] = (int)(pk & 0x7FFFFF);
    }
}

// ---------------------------------------------------------------------------
// Vector row load: guarantees dwordx4/dwordx2 regardless of what the
// compiler can prove about h's alignment.
template<int CI>
__device__ __forceinline__ void load_row(const float* __restrict__ p, float* r) {
    if constexpr (CI % 4 == 0) {
        const float4* q = (const float4*)p;
#pragma unroll
        for (int i = 0; i < CI / 4; i++) {
            float4 v = q[i];
            r[4*i] = v.x; r[4*i+1] = v.y; r[4*i+2] = v.z; r[4*i+3] = v.w;
        }
    } else if constexpr (CI % 2 == 0) {
        const float2* q = (const float2*)p;
#pragma unroll
        for (int i = 0; i < CI / 2; i++) {
            float2 v = q[i];
            r[2*i] = v.x; r[2*i+1] = v.y;
        }
    } else {
#pragma unroll
        for (int i = 0; i < CI; i++) r[i] = p[i];
    }
}

// ---------------------------------------------------------------------------
// Fused layer, lane-group parallel: G lanes per node split the neighbor
// list (shfl_xor butterfly reduce), epilogue split CO across the G lanes.
template<int CI, int CO, int G, bool IN_AFFINE, bool DO_STATS>
__global__ void layer_kernel(const int* __restrict__ row_ptr, const int* __restrict__ col,
                             const float* __restrict__ h,
                             const float* __restrict__ sc_in, const float* __restrict__ sh_in,
                             const float* __restrict__ wl, const float* __restrict__ bl,
                             const float* __restrict__ wr,
                             float* __restrict__ y,
                             float* __restrict__ stat_sum, float* __restrict__ stat_sq) {
    constexpr int NPB = 256 / G;             // nodes per block
    constexpr int OPL = (CO + G - 1) / G;    // outputs per lane

    __shared__ float sWl[CO * CI];
    __shared__ float sWr[CO * CI];
    __shared__ float sBl[CO];
    __shared__ float sSc[CI];
    __shared__ float sSh[CI];
    __shared__ float red_sum[CO];
    __shared__ float red_sq[CO];

    for (int i = threadIdx.x; i < CO * CI; i += blockDim.x) {
        sWl[i] = wl[i];
        sWr[i] = wr[i];
    }
    if (threadIdx.x < CO) {
        sBl[threadIdx.x] = bl[threadIdx.x];
        if (DO_STATS) { red_sum[threadIdx.x] = 0.0f; red_sq[threadIdx.x] = 0.0f; }
    }
    if (IN_AFFINE && threadIdx.x < CI) {
        sSc[threadIdx.x] = sc_in[threadIdx.x];
        sSh[threadIdx.x] = sh_in[threadIdx.x];
    }
    __syncthreads();

    int node = blockIdx.x * NPB + (threadIdx.x / G);
    int g    = threadIdx.x & (G - 1);
    bool valid = node < NNODES;

    float acc[CI];
#pragma unroll
    for (int c = 0; c < CI; c++) acc[c] = 0.0f;

    int beg = 0, end = 0;
    if (valid) {
        beg = row_ptr[node];
        end = row_ptr[node + 1];
        int j = beg + g;
        // U=2: two independent rows in flight per lane
        for (; j + G < end; j += 2 * G) {
            int i0 = col[j], i1 = col[j + G];
            float r0[CI], r1[CI];
            load_row<CI>(h + (long)i0 * CI, r0);
            load_row<CI>(h + (long)i1 * CI, r1);
#pragma unroll
            for (int c = 0; c < CI; c++) acc[c] += r0[c] + r1[c];
        }
        if (j < end) {
            float r0[CI];
            load_row<CI>(h + (long)col[j] * CI, r0);
#pragma unroll
            for (int c = 0; c < CI; c++) acc[c] += r0[c];
        }
    }

    // butterfly: all G lanes end with the full neighbor sum
#pragma unroll
    for (int m = 1; m < G; m <<= 1)
#pragma unroll
        for (int c = 0; c < CI; c++) acc[c] += __shfl_xor(acc[c], m);

    float out[OPL];
    float nrm2 = 0.0f;
    if (valid) {
        float ic = 1.0f / fmaxf((float)(end - beg), 1.0f);
        float xin[CI];
        load_row<CI>(h + (long)node * CI, xin);
        float agg[CI];
#pragma unroll
        for (int c = 0; c < CI; c++) {
            float a  = acc[c] * ic;
            float xv = xin[c];
            if (IN_AFFINE) {
                a  = a  * sSc[c] + sSh[c];
                xv = xv * sSc[c] + sSh[c];
            }
            agg[c] = a;
            xin[c] = xv;
        }
#pragma unroll
        for (int k = 0; k < OPL; k++) {
            int o = g * OPL + k;
            float v = 0.0f;
            if (o < CO) {
                v = sBl[o];
#pragma unroll
                for (int c = 0; c < CI; c++)
                    v += sWl[o * CI + c] * agg[c] + sWr[o * CI + c] * xin[c];
            }
            out[k] = v;
            nrm2 += v * v;
        }
    }
#pragma unroll
    for (int m = 1; m < G; m <<= 1) nrm2 += __shfl_xor(nrm2, m);

    if (valid) {
        float inv_nrm = 1.0f / fmaxf(sqrtf(nrm2), L2_EPS);
#pragma unroll
        for (int k = 0; k < OPL; k++) {
            int o = g * OPL + k;
            if (o < CO) {
                float v = fmaxf(out[k] * inv_nrm, 0.0f);   // L2 norm + ReLU
                y[(long)node * CO + o] = v;
                if (DO_STATS) {
                    atomicAdd(&red_sum[o], v);
                    atomicAdd(&red_sq[o], v * v);
                }
            }
        }
    }

    if (DO_STATS) {
        __syncthreads();
        if (threadIdx.x < CO) {
            atomicAdd(&stat_sum[threadIdx.x], red_sum[threadIdx.x]);
            atomicAdd(&stat_sq[threadIdx.x], red_sq[threadIdx.x]);
        }
    }
}

// BN stats -> per-channel affine (sc, sh):  y_bn = y*sc + sh
__global__ void finalize_bn(const float* __restrict__ ssum, const float* __restrict__ ssq,
                            const float* __restrict__ g, const float* __restrict__ b,
                            float* __restrict__ sc, float* __restrict__ sh, int C) {
    int c = threadIdx.x;
    if (c < C) {
        float m = ssum[c] * (1.0f / NNODES);
        float v = ssq[c] * (1.0f / NNODES) - m * m;
        float is = 1.0f / sqrtf(v + BN_EPS);
        float s = g[c] * is;
        sc[c] = s;
        sh[c] = b[c] - m * s;
    }
}

// ---------------------------------------------------------------------------
extern "C" void kernel_launch(void* const* d_in, const int* in_sizes, int n_in,
                              void* d_out, int out_size, void* d_ws, size_t ws_size,
                              hipStream_t stream) {
    const float* x   = (const float*)d_in[0];
    const int*   ei  = (const int*)d_in[1];
    const int*   src = ei;
    const int*   dst = ei + NEDGES;

    const float* w1l = (const float*)d_in[2];
    const float* b1l = (const float*)d_in[3];
    const float* w1r = (const float*)d_in[4];
    const float* w2l = (const float*)d_in[5];
    const float* b2l = (const float*)d_in[6];
    const float* w2r = (const float*)d_in[7];
    const float* w3l = (const float*)d_in[8];
    const float* b3l = (const float*)d_in[9];
    const float* w3r = (const float*)d_in[10];
    const float* w4l = (const float*)d_in[11];
    const float* b4l = (const float*)d_in[12];
    const float* w4r = (const float*)d_in[13];
    const float* g1  = (const float*)d_in[14];
    const float* be1 = (const float*)d_in[15];
    const float* g2  = (const float*)d_in[16];
    const float* be2 = (const float*)d_in[17];
    const float* g3  = (const float*)d_in[18];
    const float* be3 = (const float*)d_in[19];

    char* w = (char*)d_ws;
    int* blk_hist     = (int*)w;  w += NBLK_E * NBKT * 4;
    int* blk_off      = (int*)w;  w += NBLK_E * NBKT * 4;
    int* bucket_total = (int*)w;  w += 256 * 4;
    int* bucket_base  = (int*)w;  w += 256 * 4;
    int* row_ptr      = (int*)w;  w += (NNODES + 8) * 4;
    int* col          = (int*)w;  w += NEDGES * 4;
    float* hA         = (float*)w; w += NNODES * 16 * 4;
    float* hB         = (float*)w; w += NNODES * 16 * 4;
    float* stats      = (float*)w; w += 3 * 128 * 4;
    unsigned int* staged = (unsigned int*)hB;  // staged edges die before hB is written

    float* ssum1 = stats + 0 * 128, *ssq1 = ssum1 + 32, *sc1 = ssq1 + 32, *sh1 = sc1 + 32;
    float* ssum2 = stats + 1 * 128, *ssq2 = ssum2 + 32, *sc2 = ssq2 + 32, *sh2 = sc2 + 32;
    float* ssum3 = stats + 2 * 128, *ssq3 = ssum3 + 32, *sc3 = ssq3 + 32, *sh3 = sc3 + 32;

    hipMemsetAsync(bucket_total, 0, 256 * 4, stream);
    hipMemsetAsync(stats, 0, 3 * 128 * 4, stream);

    hist_kernel   <<<NBLK_E, 256, 0, stream>>>(dst, blk_hist, bucket_total);
    scan_buckets  <<<1, 256, 0, stream>>>(bucket_total, bucket_base);
    scan_blocks   <<<NBKT, 512, 0, stream>>>(blk_hist, bucket_base, blk_off);
    bucket_scatter<<<NBLK_E, 256, 0, stream>>>(src, dst, blk_off, staged);
    csr_finalize  <<<NBKT, 512, 0, stream>>>(staged, bucket_base, row_ptr, col);

    // layer 1: 4 -> 6, G=4 (+stats)
    {
        constexpr int NPB = 256 / 4;
        layer_kernel<4, 6, 4, false, true><<<(NNODES + NPB - 1) / NPB, 256, 0, stream>>>(
            row_ptr, col, x, nullptr, nullptr, w1l, b1l, w1r, hA, ssum1, ssq1);
    }
    finalize_bn<<<1, 64, 0, stream>>>(ssum1, ssq1, g1, be1, sc1, sh1, 6);

    // layer 2: 6 -> 8, G=4 (+stats), BN1 folded
    {
        constexpr int NPB = 256 / 4;
        layer_kernel<6, 8, 4, true, true><<<(NNODES + NPB - 1) / NPB, 256, 0, stream>>>(
            row_ptr, col, hA, sc1, sh1, w2l, b2l, w2r, hB, ssum2, ssq2);
    }
    finalize_bn<<<1, 64, 0, stream>>>(ssum2, ssq2, g2, be2, sc2, sh2, 8);

    // layer 3: 8 -> 16, G=4 (+stats), BN2 folded
    {
        constexpr int NPB = 256 / 4;
        layer_kernel<8, 16, 4, true, true><<<(NNODES + NPB - 1) / NPB, 256, 0, stream>>>(
            row_ptr, col, hB, sc2, sh2, w3l, b3l, w3r, hA, ssum3, ssq3);
    }
    finalize_bn<<<1, 64, 0, stream>>>(ssum3, ssq3, g3, be3, sc3, sh3, 16);

    // layer 4: 16 -> 32, G=8, BN3 folded, ReLU -> d_out
    {
        constexpr int NPB = 256 / 8;
        layer_kernel<16, 32, 8, true, false><<<(NNODES + NPB - 1) / NPB, 256, 0, stream>>>(
            row_ptr, col, hA, sc3, sh3, w4l, b4l, w4r, (float*)d_out, nullptr, nullptr);
    }
}